// Round 1
// baseline (541.919 us; speedup 1.0000x reference)
//
#include <hip/hip_runtime.h>
#include <math.h>

#define NT 256

// ---------------- CSR build ----------------

__global__ void detect64_kernel(const int* __restrict__ ei, int twoE, int* __restrict__ flag) {
    // int64 little-endian storage => odd int32 words are high words == 0 (values < 2^31)
    int is64 = 1;
    for (int k = 1; k < 16 && k < twoE; k += 2)
        if (ei[k] != 0) { is64 = 0; break; }
    *flag = is64;
}

__global__ void count_kernel(const int* __restrict__ ei, int E, int N,
                             const int* __restrict__ flag, int* __restrict__ deg) {
    int e = blockIdx.x * blockDim.x + threadIdx.x;
    if (e >= E) return;
    int is64 = *flag;
    long long pos = (long long)E + e;           // dst element position
    int d = ei[is64 ? 2 * pos : pos];
    if ((unsigned)d < (unsigned)N) atomicAdd(&deg[d], 1);
}

__global__ __launch_bounds__(1024) void scan_kernel(const int* __restrict__ deg,
                                                    int* __restrict__ off,
                                                    int* __restrict__ cur, int N) {
    __shared__ int partial[1024];
    int t = threadIdx.x;
    int per = (N + 1023) >> 10;
    int base = t * per;
    int s = 0;
    for (int k = 0; k < per; k++) {
        int idx = base + k;
        if (idx < N) s += deg[idx];
    }
    partial[t] = s;
    __syncthreads();
    for (int o = 1; o < 1024; o <<= 1) {
        int v = (t >= o) ? partial[t - o] : 0;
        __syncthreads();
        partial[t] += v;
        __syncthreads();
    }
    int run = (t == 0) ? 0 : partial[t - 1];
    for (int k = 0; k < per; k++) {
        int idx = base + k;
        if (idx < N) {
            off[idx] = run;
            cur[idx] = run;
            run += deg[idx];
        }
    }
    if (t == 0) off[N] = partial[1023];
}

__global__ void fill_kernel(const int* __restrict__ ei, int E, int N,
                            const int* __restrict__ flag, int* __restrict__ cur,
                            int* __restrict__ esrc) {
    int e = blockIdx.x * blockDim.x + threadIdx.x;
    if (e >= E) return;
    int is64 = *flag;
    long long spos = e;
    long long dpos = (long long)E + e;
    int s = ei[is64 ? 2 * spos : spos];
    int d = ei[is64 ? 2 * dpos : dpos];
    if ((unsigned)d >= (unsigned)N || (unsigned)s >= (unsigned)N) return;
    int p = atomicAdd(&cur[d], 1);
    esrc[p] = s;
}

// ---------------- GEMM: xl = x@Wl+bl, xr = x@Wr+br ----------------
// grid (ceil(N/64), 4); block 256. blockIdx.y: 0,1 -> xl cols [0,64),[64,128); 2,3 -> xr.

__global__ __launch_bounds__(256) void gemm_xlxr(const float* __restrict__ x,
                                                 const float* __restrict__ Wl,
                                                 const float* __restrict__ bl,
                                                 const float* __restrict__ Wr,
                                                 const float* __restrict__ br,
                                                 float* __restrict__ xl,
                                                 float* __restrict__ xr, int N) {
    int row0 = blockIdx.x * 64;
    int yb = blockIdx.y;
    const float* W = (yb < 2) ? Wl : Wr;
    const float* bias = (yb < 2) ? bl : br;
    float* out = (yb < 2) ? xl : xr;
    int col0 = (yb & 1) * 64;

    __shared__ float Xs[64][33];
    __shared__ float Ws[32][64];

    int t = threadIdx.x;
    int tx = t & 15, ty = t >> 4;

    float acc[4][4];
#pragma unroll
    for (int i = 0; i < 4; i++)
#pragma unroll
        for (int j = 0; j < 4; j++) acc[i][j] = 0.f;

    for (int k0 = 0; k0 < 128; k0 += 32) {
        for (int idx = t; idx < 64 * 32; idx += 256) {
            int r = idx >> 5, c = idx & 31;
            int gr = row0 + r;
            Xs[r][c] = (gr < N) ? x[(long long)gr * 128 + k0 + c] : 0.f;
        }
        for (int idx = t; idx < 32 * 64; idx += 256) {
            int r = idx >> 6, c = idx & 63;
            Ws[r][c] = W[(k0 + r) * 128 + col0 + c];
        }
        __syncthreads();
#pragma unroll
        for (int k = 0; k < 32; k++) {
            float a[4], b[4];
#pragma unroll
            for (int i = 0; i < 4; i++) a[i] = Xs[ty + i * 16][k];
#pragma unroll
            for (int j = 0; j < 4; j++) b[j] = Ws[k][tx + j * 16];
#pragma unroll
            for (int i = 0; i < 4; i++)
#pragma unroll
                for (int j = 0; j < 4; j++) acc[i][j] += a[i] * b[j];
        }
        __syncthreads();
    }

#pragma unroll
    for (int i = 0; i < 4; i++) {
        int gr = row0 + ty + i * 16;
        if (gr < N) {
#pragma unroll
            for (int j = 0; j < 4; j++) {
                int c = col0 + tx + j * 16;
                out[(long long)gr * 128 + c] = acc[i][j] + bias[c];
            }
        }
    }
}

// ---------------- GATv2 aggregation (online softmax, per-dst block) ----------------
// grid N, block 128; thread t -> head h = t>>4, dim d = t&15.

__global__ __launch_bounds__(128) void gat_agg(const float* __restrict__ xl,
                                               const float* __restrict__ xr,
                                               const int* __restrict__ off,
                                               const int* __restrict__ esrc,
                                               const float* __restrict__ att,
                                               const float* __restrict__ bias,
                                               float* __restrict__ out, int N) {
    int i = blockIdx.x;
    int t = threadIdx.x;
    float xr_t = xr[(long long)i * 128 + t];
    float att_t = att[t];

    float m = -INFINITY, s = 0.f, acc = 0.f;
    int start = off[i], cnt = off[i + 1] - start;

    for (int j = -1; j < cnt; j++) {
        int src = (j < 0) ? i : esrc[start + j];
        float xlj = xl[(long long)src * 128 + t];
        float z = xlj + xr_t;
        z = (z > 0.f) ? z : 0.2f * z;
        float p = z * att_t;
        p += __shfl_xor(p, 1, 64);
        p += __shfl_xor(p, 2, 64);
        p += __shfl_xor(p, 4, 64);
        p += __shfl_xor(p, 8, 64);
        float e = p;  // sum over the 16 lanes of this head
        float mn = fmaxf(m, e);
        float sc = __expf(m - mn);
        float w = __expf(e - mn);
        s = s * sc + w;
        acc = acc * sc + w * xlj;
        m = mn;
    }
    out[(long long)i * 128 + t] = acc / (s + 1e-16f) + bias[t];
}

// ---------------- head ----------------

__global__ __launch_bounds__(128) void head_kernel(const float* __restrict__ x,
                                                   const float* __restrict__ w,
                                                   const float* __restrict__ bh,
                                                   const int* __restrict__ nch,
                                                   float* __restrict__ out) {
    __shared__ float r[2];
    int b = blockIdx.x, t = threadIdx.x;
    int chunk = 2 + nch[0];
    int row = (b >> 1) * chunk + (b & 1);
    float p = x[(long long)row * 128 + t] * w[t];
#pragma unroll
    for (int o = 32; o >= 1; o >>= 1) p += __shfl_xor(p, o, 64);
    if ((t & 63) == 0) r[t >> 6] = p;
    __syncthreads();
    if (t == 0) out[b] = r[0] + r[1] + bh[0];
}

// ---------------- launch ----------------

extern "C" void kernel_launch(void* const* d_in, const int* in_sizes, int n_in,
                              void* d_out, int out_size, void* d_ws, size_t ws_size,
                              hipStream_t stream) {
    const float* x0 = (const float*)d_in[0];
    const int* ei = (const int*)d_in[1];
    const int* nchunks = (const int*)d_in[2];
    const float* Wl = (const float*)d_in[3];
    const float* bl = (const float*)d_in[4];
    const float* Wr = (const float*)d_in[5];
    const float* br = (const float*)d_in[6];
    const float* att = (const float*)d_in[7];
    const float* bias = (const float*)d_in[8];
    const float* wh = (const float*)d_in[9];
    const float* bh = (const float*)d_in[10];

    const int D = 128;
    int N = in_sizes[0] / D;   // 10000
    int E = in_sizes[1] / 2;   // 160000

    size_t fN = (size_t)N * D;
    float* xl = (float*)d_ws;
    float* xr = xl + fN;
    float* xA = xr + fN;
    int* deg = (int*)(xA + fN);
    int* off = deg + N;
    int* cur = off + N + 1;
    int* esrc = cur + N;
    int* flag = esrc + E;

    // CSR build (once; dst is layer-invariant)
    hipMemsetAsync(deg, 0, (size_t)N * sizeof(int), stream);
    detect64_kernel<<<1, 1, 0, stream>>>(ei, 2 * E, flag);
    count_kernel<<<(E + NT - 1) / NT, NT, 0, stream>>>(ei, E, N, flag, deg);
    scan_kernel<<<1, 1024, 0, stream>>>(deg, off, cur, N);
    fill_kernel<<<(E + NT - 1) / NT, NT, 0, stream>>>(ei, E, N, flag, cur, esrc);

    dim3 ggrid((N + 63) / 64, 4);
    const float* xc = x0;
    for (int l = 0; l < 7; l++) {
        gemm_xlxr<<<ggrid, 256, 0, stream>>>(xc, Wl + (size_t)l * D * D, bl + (size_t)l * D,
                                             Wr + (size_t)l * D * D, br + (size_t)l * D,
                                             xl, xr, N);
        gat_agg<<<N, 128, 0, stream>>>(xl, xr, off, esrc, att + (size_t)l * D,
                                       bias + (size_t)l * D, xA, N);
        xc = xA;
    }

    head_kernel<<<out_size, 128, 0, stream>>>(xc, wh, bh, nchunks, (float*)d_out);
}

// Round 2
// 403.275 us; speedup vs baseline: 1.3438x; 1.3438x over previous
//
#include <hip/hip_runtime.h>
#include <math.h>

#define NT 256

// ---------------- CSR build ----------------

__global__ void detect64_kernel(const int* __restrict__ ei, int twoE, int* __restrict__ flag) {
    int is64 = 1;
    for (int k = 1; k < 16 && k < twoE; k += 2)
        if (ei[k] != 0) { is64 = 0; break; }
    *flag = is64;
}

__global__ void count_kernel(const int* __restrict__ ei, int E, int N,
                             const int* __restrict__ flag, int* __restrict__ deg) {
    int e = blockIdx.x * blockDim.x + threadIdx.x;
    if (e >= E) return;
    int is64 = *flag;
    long long pos = (long long)E + e;
    int d = ei[is64 ? 2 * pos : pos];
    if ((unsigned)d < (unsigned)N) atomicAdd(&deg[d], 1);
}

__global__ __launch_bounds__(1024) void scan_kernel(const int* __restrict__ deg,
                                                    int* __restrict__ off,
                                                    int* __restrict__ cur, int N) {
    __shared__ int partial[1024];
    int t = threadIdx.x;
    int per = (N + 1023) >> 10;
    int base = t * per;
    int s = 0;
    for (int k = 0; k < per; k++) {
        int idx = base + k;
        if (idx < N) s += deg[idx];
    }
    partial[t] = s;
    __syncthreads();
    for (int o = 1; o < 1024; o <<= 1) {
        int v = (t >= o) ? partial[t - o] : 0;
        __syncthreads();
        partial[t] += v;
        __syncthreads();
    }
    int run = (t == 0) ? 0 : partial[t - 1];
    for (int k = 0; k < per; k++) {
        int idx = base + k;
        if (idx < N) {
            off[idx] = run;
            cur[idx] = run;
            run += deg[idx];
        }
    }
    if (t == 0) off[N] = partial[1023];
}

__global__ void fill_kernel(const int* __restrict__ ei, int E, int N,
                            const int* __restrict__ flag, int* __restrict__ cur,
                            int* __restrict__ esrc) {
    int e = blockIdx.x * blockDim.x + threadIdx.x;
    if (e >= E) return;
    int is64 = *flag;
    long long spos = e;
    long long dpos = (long long)E + e;
    int s = ei[is64 ? 2 * spos : spos];
    int d = ei[is64 ? 2 * dpos : dpos];
    if ((unsigned)d >= (unsigned)N || (unsigned)s >= (unsigned)N) return;
    int p = atomicAdd(&cur[d], 1);
    esrc[p] = s;
}

// ---------------- GEMM: xl = x@Wl+bl, xr = x@Wr+br ----------------
// Tile 64 rows x 32 cols, block 128 threads, grid (ceil(N/64), 8).
// blockIdx.y: bit2 -> {l,r}; bits 0..1 -> col block of 32.
// Inner loop: 2x ds_read_b128 per k (VALU-bound, 16 v_fma per k).

__global__ __launch_bounds__(128) void gemm_xlxr(const float* __restrict__ x,
                                                 const float* __restrict__ Wl,
                                                 const float* __restrict__ bl,
                                                 const float* __restrict__ Wr,
                                                 const float* __restrict__ br,
                                                 float* __restrict__ xl,
                                                 float* __restrict__ xr, int N) {
    int row0 = blockIdx.x * 64;
    int yb = blockIdx.y;
    const float* W = (yb < 4) ? Wl : Wr;
    const float* bias = (yb < 4) ? bl : br;
    float* out = (yb < 4) ? xl : xr;
    int col0 = (yb & 3) * 32;

    __shared__ float Xs[32][68];   // [k][row], stride 68 floats = 272B (16B aligned)
    __shared__ float Ws[32][32];   // [k][col]

    int t = threadIdx.x;
    int tx = t & 7;    // col group (4 cols each)
    int ry = t >> 3;   // row group (4 rows each), 0..15

    float acc[4][4];
#pragma unroll
    for (int i = 0; i < 4; i++)
#pragma unroll
        for (int j = 0; j < 4; j++) acc[i][j] = 0.f;

    int gsta = t & 7;      // k-group for X staging
    int rsta = t >> 3;     // row base for X staging

    for (int k0 = 0; k0 < 128; k0 += 32) {
        // stage X tile transposed: Xs[k][r]
#pragma unroll
        for (int it = 0; it < 4; it++) {
            int r = rsta + it * 16;
            int gr = row0 + r;
            float4 v = make_float4(0.f, 0.f, 0.f, 0.f);
            if (gr < N) v = *(const float4*)&x[(size_t)gr * 128 + k0 + gsta * 4];
            Xs[gsta * 4 + 0][r] = v.x;
            Xs[gsta * 4 + 1][r] = v.y;
            Xs[gsta * 4 + 2][r] = v.z;
            Xs[gsta * 4 + 3][r] = v.w;
        }
        // stage W tile: Ws[k][c]
#pragma unroll
        for (int it = 0; it < 2; it++) {
            int kk = rsta + it * 16;
            *(float4*)&Ws[kk][gsta * 4] =
                *(const float4*)&W[(size_t)(k0 + kk) * 128 + col0 + gsta * 4];
        }
        __syncthreads();
#pragma unroll
        for (int k = 0; k < 32; k++) {
            float4 a = *(const float4*)&Xs[k][ry * 4];
            float4 b = *(const float4*)&Ws[k][tx * 4];
            float av[4] = {a.x, a.y, a.z, a.w};
            float bv[4] = {b.x, b.y, b.z, b.w};
#pragma unroll
            for (int i = 0; i < 4; i++)
#pragma unroll
                for (int j = 0; j < 4; j++) acc[i][j] += av[i] * bv[j];
        }
        __syncthreads();
    }

    float4 bcol = *(const float4*)&bias[col0 + tx * 4];
    float bv[4] = {bcol.x, bcol.y, bcol.z, bcol.w};
#pragma unroll
    for (int i = 0; i < 4; i++) {
        int gr = row0 + ry * 4 + i;
        if (gr < N) {
            float4 o = make_float4(acc[i][0] + bv[0], acc[i][1] + bv[1],
                                   acc[i][2] + bv[2], acc[i][3] + bv[3]);
            *(float4*)&out[(size_t)gr * 128 + col0 + tx * 4] = o;
        }
    }
}

// ---------------- GATv2 aggregation ----------------
// softmax without running max (logits clamped to +-80; mathematically identical).
// Block 256 = 4 waves, wave w handles node blockIdx.x*4+w. Lane l holds dims 2l,2l+1.
// Head h = lane>>3; reduce over 8 lanes (16 dims) with 3 shfl_xor.

__global__ __launch_bounds__(256) void gat_agg(const float2* __restrict__ xl2,
                                               const float2* __restrict__ xr2,
                                               const int* __restrict__ off,
                                               const int* __restrict__ esrc,
                                               const float2* __restrict__ att2,
                                               const float2* __restrict__ bias2,
                                               float2* __restrict__ out2, int N) {
    int lane = threadIdx.x & 63;
    int i = blockIdx.x * 4 + (threadIdx.x >> 6);
    if (i >= N) return;

    float2 xr_t = xr2[(size_t)i * 64 + lane];
    float2 att_t = att2[lane];
    int start = off[i];
    int cnt = off[i + 1] - start;

    float s = 0.f, ax = 0.f, ay = 0.f;
    // process self-loop first, then cnt edges; 1-deep prefetch of the next src row
    float2 v = xl2[(size_t)i * 64 + lane];
    for (int j = 0; j <= cnt; j++) {
        int src_next = (j < cnt) ? esrc[start + j] : i;
        float2 vn = xl2[(size_t)src_next * 64 + lane];   // independent of softmax chain
        float zx = v.x + xr_t.x;
        float zy = v.y + xr_t.y;
        zx = (zx > 0.f) ? zx : 0.2f * zx;
        zy = (zy > 0.f) ? zy : 0.2f * zy;
        float p = zx * att_t.x + zy * att_t.y;
        p += __shfl_xor(p, 1, 64);
        p += __shfl_xor(p, 2, 64);
        p += __shfl_xor(p, 4, 64);
        p = fminf(fmaxf(p, -80.f), 80.f);
        float w = __expf(p);
        s += w;
        ax += w * v.x;
        ay += w * v.y;
        v = vn;
    }
    float inv = 1.f / (s + 1e-16f);
    float2 b = bias2[lane];
    float2 o;
    o.x = ax * inv + b.x;
    o.y = ay * inv + b.y;
    out2[(size_t)i * 64 + lane] = o;
}

// ---------------- head ----------------

__global__ __launch_bounds__(128) void head_kernel(const float* __restrict__ x,
                                                   const float* __restrict__ w,
                                                   const float* __restrict__ bh,
                                                   const int* __restrict__ nch,
                                                   float* __restrict__ out) {
    __shared__ float r[2];
    int b = blockIdx.x, t = threadIdx.x;
    int chunk = 2 + nch[0];
    int row = (b >> 1) * chunk + (b & 1);
    float p = x[(size_t)row * 128 + t] * w[t];
#pragma unroll
    for (int o = 32; o >= 1; o >>= 1) p += __shfl_xor(p, o, 64);
    if ((t & 63) == 0) r[t >> 6] = p;
    __syncthreads();
    if (t == 0) out[b] = r[0] + r[1] + bh[0];
}

// ---------------- launch ----------------

extern "C" void kernel_launch(void* const* d_in, const int* in_sizes, int n_in,
                              void* d_out, int out_size, void* d_ws, size_t ws_size,
                              hipStream_t stream) {
    const float* x0 = (const float*)d_in[0];
    const int* ei = (const int*)d_in[1];
    const int* nchunks = (const int*)d_in[2];
    const float* Wl = (const float*)d_in[3];
    const float* bl = (const float*)d_in[4];
    const float* Wr = (const float*)d_in[5];
    const float* br = (const float*)d_in[6];
    const float* att = (const float*)d_in[7];
    const float* bias = (const float*)d_in[8];
    const float* wh = (const float*)d_in[9];
    const float* bh = (const float*)d_in[10];

    const int D = 128;
    int N = in_sizes[0] / D;   // 10000
    int E = in_sizes[1] / 2;   // 160000

    size_t fN = (size_t)N * D;
    float* xl = (float*)d_ws;
    float* xr = xl + fN;
    float* xA = xr + fN;
    int* deg = (int*)(xA + fN);
    int* off = deg + N;
    int* cur = off + N + 1;
    int* esrc = cur + N;
    int* flag = esrc + E;

    hipMemsetAsync(deg, 0, (size_t)N * sizeof(int), stream);
    detect64_kernel<<<1, 1, 0, stream>>>(ei, 2 * E, flag);
    count_kernel<<<(E + NT - 1) / NT, NT, 0, stream>>>(ei, E, N, flag, deg);
    scan_kernel<<<1, 1024, 0, stream>>>(deg, off, cur, N);
    fill_kernel<<<(E + NT - 1) / NT, NT, 0, stream>>>(ei, E, N, flag, cur, esrc);

    dim3 ggrid((N + 63) / 64, 8);
    int aggblocks = (N + 3) / 4;
    const float* xc = x0;
    for (int l = 0; l < 7; l++) {
        gemm_xlxr<<<ggrid, 128, 0, stream>>>(xc, Wl + (size_t)l * D * D, bl + (size_t)l * D,
                                             Wr + (size_t)l * D * D, br + (size_t)l * D,
                                             xl, xr, N);
        gat_agg<<<aggblocks, 256, 0, stream>>>((const float2*)xl, (const float2*)xr, off, esrc,
                                               (const float2*)(att + (size_t)l * D),
                                               (const float2*)(bias + (size_t)l * D),
                                               (float2*)xA, N);
        xc = xA;
    }

    head_kernel<<<out_size, 128, 0, stream>>>(xc, wh, bh, nchunks, (float*)d_out);
}

// Round 3
// 385.806 us; speedup vs baseline: 1.4046x; 1.0453x over previous
//
#include <hip/hip_runtime.h>
#include <math.h>

#define NT 256

// ---------------- CSR build ----------------

__global__ void detect64_kernel(const int* __restrict__ ei, int twoE, int* __restrict__ flag) {
    int is64 = 1;
    for (int k = 1; k < 16 && k < twoE; k += 2)
        if (ei[k] != 0) { is64 = 0; break; }
    *flag = is64;
}

__global__ void count_kernel(const int* __restrict__ ei, int E, int N,
                             const int* __restrict__ flag, int* __restrict__ deg) {
    int e = blockIdx.x * blockDim.x + threadIdx.x;
    if (e >= E) return;
    int is64 = *flag;
    long long pos = (long long)E + e;
    int d = ei[is64 ? 2 * pos : pos];
    if ((unsigned)d < (unsigned)N) atomicAdd(&deg[d], 1);
}

__global__ __launch_bounds__(1024) void scan_kernel(const int* __restrict__ deg,
                                                    int* __restrict__ off,
                                                    int* __restrict__ cur, int N) {
    __shared__ int partial[1024];
    int t = threadIdx.x;
    int per = (N + 1023) >> 10;
    int base = t * per;
    int s = 0;
    for (int k = 0; k < per; k++) {
        int idx = base + k;
        if (idx < N) s += deg[idx];
    }
    partial[t] = s;
    __syncthreads();
    for (int o = 1; o < 1024; o <<= 1) {
        int v = (t >= o) ? partial[t - o] : 0;
        __syncthreads();
        partial[t] += v;
        __syncthreads();
    }
    int run = (t == 0) ? 0 : partial[t - 1];
    for (int k = 0; k < per; k++) {
        int idx = base + k;
        if (idx < N) {
            off[idx] = run;
            cur[idx] = run;
            run += deg[idx];
        }
    }
    if (t == 0) off[N] = partial[1023];
}

__global__ void fill_kernel(const int* __restrict__ ei, int E, int N,
                            const int* __restrict__ flag, int* __restrict__ cur,
                            int* __restrict__ esrc) {
    int e = blockIdx.x * blockDim.x + threadIdx.x;
    if (e >= E) return;
    int is64 = *flag;
    long long spos = e;
    long long dpos = (long long)E + e;
    int s = ei[is64 ? 2 * spos : spos];
    int d = ei[is64 ? 2 * dpos : dpos];
    if ((unsigned)d >= (unsigned)N || (unsigned)s >= (unsigned)N) return;
    int p = atomicAdd(&cur[d], 1);
    esrc[p] = s;
}

// ---------------- GEMM: one block does 32 rows x 256 cols (xl | xr) ----------------
// block 256 = ty(0..7 row-groups of 4) x tx(0..31 col-groups of 8)
// LDS: Xs transposed [k][row] (stride 36), Ws [k][col 0..255] (stride 260).
// Per k: 1 + 2 ds_read_b128, 32 v_fma -> VALU-bound.

__global__ __launch_bounds__(256) void gemm_xlxr(const float* __restrict__ x,
                                                 const float* __restrict__ Wl,
                                                 const float* __restrict__ bl,
                                                 const float* __restrict__ Wr,
                                                 const float* __restrict__ br,
                                                 float* __restrict__ xl,
                                                 float* __restrict__ xr, int N) {
    int row0 = blockIdx.x * 32;

    __shared__ float Xs[32][36];    // [k][row]
    __shared__ float Ws[32][260];   // [k][col], cols 0..127 = Wl, 128..255 = Wr

    int t = threadIdx.x;
    int tx = t & 31;   // col group (8 cols)
    int ty = t >> 5;   // row group (4 rows)

    float acc[4][8];
#pragma unroll
    for (int i = 0; i < 4; i++)
#pragma unroll
        for (int j = 0; j < 8; j++) acc[i][j] = 0.f;

    int xr_row = t >> 3;     // 0..31
    int xk = t & 7;          // k-group of 4
    int wc = t & 63;         // col group of 4 (0..63 -> 256 cols)
    int wk = t >> 6;         // 0..3

    for (int k0 = 0; k0 < 128; k0 += 32) {
        // stage X transposed
        {
            int gr = row0 + xr_row;
            float4 v = make_float4(0.f, 0.f, 0.f, 0.f);
            if (gr < N) v = *(const float4*)&x[(size_t)gr * 128 + k0 + xk * 4];
            Xs[xk * 4 + 0][xr_row] = v.x;
            Xs[xk * 4 + 1][xr_row] = v.y;
            Xs[xk * 4 + 2][xr_row] = v.z;
            Xs[xk * 4 + 3][xr_row] = v.w;
        }
        // stage W panels (contiguous b128 writes, conflict-free)
#pragma unroll
        for (int it = 0; it < 8; it++) {
            int kk = wk + it * 4;
            const float* Wsrc = (wc < 32) ? &Wl[(size_t)(k0 + kk) * 128 + wc * 4]
                                          : &Wr[(size_t)(k0 + kk) * 128 + (wc - 32) * 4];
            *(float4*)&Ws[kk][wc * 4] = *(const float4*)Wsrc;
        }
        __syncthreads();
#pragma unroll
        for (int k = 0; k < 32; k++) {
            float4 a4 = *(const float4*)&Xs[k][ty * 4];
            float4 b0 = *(const float4*)&Ws[k][tx * 8];
            float4 b1 = *(const float4*)&Ws[k][tx * 8 + 4];
            float a[4] = {a4.x, a4.y, a4.z, a4.w};
            float b[8] = {b0.x, b0.y, b0.z, b0.w, b1.x, b1.y, b1.z, b1.w};
#pragma unroll
            for (int i = 0; i < 4; i++)
#pragma unroll
                for (int j = 0; j < 8; j++) acc[i][j] += a[i] * b[j];
        }
        __syncthreads();
    }

    // epilogue: cols tx*8..tx*8+7; col<128 -> xl, else xr
    int c0 = tx * 8;
    const float* bias0 = (c0 < 128) ? &bl[c0] : &br[c0 - 128];
    const float* bias1 = (c0 + 4 < 128) ? &bl[c0 + 4] : &br[c0 + 4 - 128];
    float4 bv0 = *(const float4*)bias0;
    float4 bv1 = *(const float4*)bias1;
    float* out0 = (c0 < 128) ? xl : xr;
    float* out1 = (c0 + 4 < 128) ? xl : xr;
    int cc0 = (c0 < 128) ? c0 : c0 - 128;
    int cc1 = (c0 + 4 < 128) ? c0 + 4 : c0 + 4 - 128;
#pragma unroll
    for (int i = 0; i < 4; i++) {
        int gr = row0 + ty * 4 + i;
        if (gr < N) {
            float4 o0 = make_float4(acc[i][0] + bv0.x, acc[i][1] + bv0.y,
                                    acc[i][2] + bv0.z, acc[i][3] + bv0.w);
            float4 o1 = make_float4(acc[i][4] + bv1.x, acc[i][5] + bv1.y,
                                    acc[i][6] + bv1.z, acc[i][7] + bv1.w);
            *(float4*)&out0[(size_t)gr * 128 + cc0] = o0;
            *(float4*)&out1[(size_t)gr * 128 + cc1] = o1;
        }
    }
}

// ---------------- GATv2 aggregation: 2 edges per wave-iteration ----------------
// Wave = 1 node. half = lane>>5 picks edge 2j+half; cl = lane&31 holds dims 4cl..4cl+3.
// Head h = cl>>2 (4 lanes/head): reduce p with 2 shfl_xor. Softmax without running max
// (logits clamped to +-80). Final cross-half combine via shfl_xor 32.

__global__ __launch_bounds__(256) void gat_agg(const float4* __restrict__ xl4,
                                               const float4* __restrict__ xr4,
                                               const int* __restrict__ off,
                                               const int* __restrict__ esrc,
                                               const float4* __restrict__ att4,
                                               const float4* __restrict__ bias4,
                                               float4* __restrict__ out4, int N) {
    int lane = threadIdx.x & 63;
    int half = lane >> 5;
    int cl = lane & 31;
    int i = blockIdx.x * 4 + (threadIdx.x >> 6);
    if (i >= N) return;

    float4 xr_t = xr4[(size_t)i * 32 + cl];
    float4 att_t = att4[cl];
    int start = off[i];
    int total = off[i + 1] - start + 1;   // + self-loop (slot 0)
    int pairs = (total + 1) >> 1;

    float s = 0.f;
    float4 acc = make_float4(0.f, 0.f, 0.f, 0.f);

    // prefetch slot for pair 0
    int k = half;
    int src = (k < total) ? ((k == 0) ? i : esrc[start + k - 1]) : i;
    float4 v = xl4[(size_t)src * 32 + cl];
    int valid = (k < total);

    for (int jj = 0; jj < pairs; jj++) {
        // prefetch next pair (independent of current compute)
        int kn = 2 * (jj + 1) + half;
        int srcn = (kn < total) ? ((kn == 0) ? i : esrc[start + kn - 1]) : i;
        float4 vn = xl4[(size_t)srcn * 32 + cl];
        int validn = (kn < total);

        float zx = v.x + xr_t.x, zy = v.y + xr_t.y;
        float zz = v.z + xr_t.z, zw = v.w + xr_t.w;
        zx = (zx > 0.f) ? zx : 0.2f * zx;
        zy = (zy > 0.f) ? zy : 0.2f * zy;
        zz = (zz > 0.f) ? zz : 0.2f * zz;
        zw = (zw > 0.f) ? zw : 0.2f * zw;
        float p = zx * att_t.x + zy * att_t.y + zz * att_t.z + zw * att_t.w;
        p += __shfl_xor(p, 1, 64);
        p += __shfl_xor(p, 2, 64);
        p = fminf(fmaxf(p, -80.f), 80.f);
        float w = valid ? __expf(p) : 0.f;
        s += w;
        acc.x += w * v.x;
        acc.y += w * v.y;
        acc.z += w * v.z;
        acc.w += w * v.w;

        v = vn;
        valid = validn;
    }

    // combine the two halves
    s += __shfl_xor(s, 32, 64);
    acc.x += __shfl_xor(acc.x, 32, 64);
    acc.y += __shfl_xor(acc.y, 32, 64);
    acc.z += __shfl_xor(acc.z, 32, 64);
    acc.w += __shfl_xor(acc.w, 32, 64);

    if (half == 0) {
        float inv = 1.f / (s + 1e-16f);
        float4 b = bias4[cl];
        float4 o;
        o.x = acc.x * inv + b.x;
        o.y = acc.y * inv + b.y;
        o.z = acc.z * inv + b.z;
        o.w = acc.w * inv + b.w;
        out4[(size_t)i * 32 + cl] = o;
    }
}

// ---------------- head ----------------

__global__ __launch_bounds__(128) void head_kernel(const float* __restrict__ x,
                                                   const float* __restrict__ w,
                                                   const float* __restrict__ bh,
                                                   const int* __restrict__ nch,
                                                   float* __restrict__ out) {
    __shared__ float r[2];
    int b = blockIdx.x, t = threadIdx.x;
    int chunk = 2 + nch[0];
    int row = (b >> 1) * chunk + (b & 1);
    float p = x[(size_t)row * 128 + t] * w[t];
#pragma unroll
    for (int o = 32; o >= 1; o >>= 1) p += __shfl_xor(p, o, 64);
    if ((t & 63) == 0) r[t >> 6] = p;
    __syncthreads();
    if (t == 0) out[b] = r[0] + r[1] + bh[0];
}

// ---------------- launch ----------------

extern "C" void kernel_launch(void* const* d_in, const int* in_sizes, int n_in,
                              void* d_out, int out_size, void* d_ws, size_t ws_size,
                              hipStream_t stream) {
    const float* x0 = (const float*)d_in[0];
    const int* ei = (const int*)d_in[1];
    const int* nchunks = (const int*)d_in[2];
    const float* Wl = (const float*)d_in[3];
    const float* bl = (const float*)d_in[4];
    const float* Wr = (const float*)d_in[5];
    const float* br = (const float*)d_in[6];
    const float* att = (const float*)d_in[7];
    const float* bias = (const float*)d_in[8];
    const float* wh = (const float*)d_in[9];
    const float* bh = (const float*)d_in[10];

    const int D = 128;
    int N = in_sizes[0] / D;   // 10000
    int E = in_sizes[1] / 2;   // 160000

    size_t fN = (size_t)N * D;
    float* xl = (float*)d_ws;
    float* xr = xl + fN;
    float* xA = xr + fN;
    int* deg = (int*)(xA + fN);
    int* off = deg + N;
    int* cur = off + N + 1;
    int* esrc = cur + N;
    int* flag = esrc + E;

    hipMemsetAsync(deg, 0, (size_t)N * sizeof(int), stream);
    detect64_kernel<<<1, 1, 0, stream>>>(ei, 2 * E, flag);
    count_kernel<<<(E + NT - 1) / NT, NT, 0, stream>>>(ei, E, N, flag, deg);
    scan_kernel<<<1, 1024, 0, stream>>>(deg, off, cur, N);
    fill_kernel<<<(E + NT - 1) / NT, NT, 0, stream>>>(ei, E, N, flag, cur, esrc);

    int gblocks = (N + 31) / 32;
    int aggblocks = (N + 3) / 4;
    const float* xc = x0;
    for (int l = 0; l < 7; l++) {
        gemm_xlxr<<<gblocks, 256, 0, stream>>>(xc, Wl + (size_t)l * D * D, bl + (size_t)l * D,
                                               Wr + (size_t)l * D * D, br + (size_t)l * D,
                                               xl, xr, N);
        gat_agg<<<aggblocks, 256, 0, stream>>>((const float4*)xl, (const float4*)xr, off, esrc,
                                               (const float4*)(att + (size_t)l * D),
                                               (const float4*)(bias + (size_t)l * D),
                                               (float4*)xA, N);
        xc = xA;
    }

    head_kernel<<<out_size, 128, 0, stream>>>(xc, wh, bh, nchunks, (float*)d_out);
}

// Round 4
// 331.340 us; speedup vs baseline: 1.6355x; 1.1644x over previous
//
#include <hip/hip_runtime.h>
#include <math.h>

#define NT 256

typedef __attribute__((ext_vector_type(8))) short bf16x8;
typedef __attribute__((ext_vector_type(4))) float f32x4;

// ---------------- CSR build ----------------

__device__ inline int detect_is64(const int* __restrict__ ei) {
    // int64 little-endian => odd int32 words (high words) are all 0 for values < 2^31
    int is64 = 1;
#pragma unroll
    for (int k = 1; k < 16; k += 2) is64 &= (ei[k] == 0);
    return is64;
}

__global__ void count_kernel(const int* __restrict__ ei, int E, int N,
                             int* __restrict__ deg) {
    int e = blockIdx.x * blockDim.x + threadIdx.x;
    if (e >= E) return;
    int is64 = detect_is64(ei);
    long long pos = (long long)E + e;
    int d = ei[is64 ? 2 * pos : pos];
    if ((unsigned)d < (unsigned)N) atomicAdd(&deg[d], 1);
}

__global__ __launch_bounds__(256) void scan_kernel(const int* __restrict__ deg,
                                                   int* __restrict__ off,
                                                   int* __restrict__ cur, int N) {
    __shared__ int wsum[4];
    __shared__ int total_s;
    int t = threadIdx.x;
    int per = (N + 255) >> 8;
    int b0 = t * per;
    int s = 0;
    for (int k = 0; k < per; k++) {
        int idx = b0 + k;
        if (idx < N) s += deg[idx];
    }
    int lane = t & 63, w = t >> 6;
    int v = s;
#pragma unroll
    for (int o = 1; o < 64; o <<= 1) {
        int u = __shfl_up(v, o, 64);
        if (lane >= o) v += u;
    }
    if (lane == 63) wsum[w] = v;
    __syncthreads();
    if (t == 0) {
        int r = 0;
#pragma unroll
        for (int j = 0; j < 4; j++) { int xx = wsum[j]; wsum[j] = r; r += xx; }
        total_s = r;
        off[N] = r;
    }
    __syncthreads();
    int run = v - s + wsum[w];   // exclusive prefix for this thread
    for (int k = 0; k < per; k++) {
        int idx = b0 + k;
        if (idx < N) {
            off[idx] = run;
            cur[idx] = run;
            run += deg[idx];
        }
    }
}

__global__ void fill_kernel(const int* __restrict__ ei, int E, int N,
                            int* __restrict__ cur, int* __restrict__ esrc) {
    int e = blockIdx.x * blockDim.x + threadIdx.x;
    if (e >= E) return;
    int is64 = detect_is64(ei);
    long long spos = e;
    long long dpos = (long long)E + e;
    int s = ei[is64 ? 2 * spos : spos];
    int d = ei[is64 ? 2 * dpos : dpos];
    if ((unsigned)d >= (unsigned)N || (unsigned)s >= (unsigned)N) return;
    int p = atomicAdd(&cur[d], 1);
    esrc[p] = s;
}

// ---------------- GEMM via bf16x3 MFMA (no LDS, no barriers) ----------------
// D = x @ [Wl | Wr] (K=128, 256 cols) with fp32 emulated as A_hi*B_hi + A_lo*B_hi + A_hi*B_lo.
// Grid 256 x 512 threads; wave w owns cols [32w,32w+32) as two 16x16 MFMA col-tiles.
// B fragments (hi+lo, full K) live in VGPRs for the whole kernel. A loads stream
// from global (16B/lane) with 1-deep row-tile pipeline. Stores direct to xl/xr.

__device__ inline void cvt8(const float4& a, const float4& b, bf16x8& hi, bf16x8& lo) {
    float f[8] = {a.x, a.y, a.z, a.w, b.x, b.y, b.z, b.w};
#pragma unroll
    for (int j = 0; j < 8; j++) {
        unsigned u = __float_as_uint(f[j]);
        hi[j] = (short)(u >> 16);                         // truncate to bf16
        float fl = f[j] - __uint_as_float(u & 0xffff0000u);
        lo[j] = (short)(__float_as_uint(fl) >> 16);       // residual, truncated
    }
}

__global__ __launch_bounds__(512, 2) void gemm_xlxr(const float* __restrict__ x,
                                                    const float* __restrict__ Wl_,
                                                    const float* __restrict__ blv,
                                                    const float* __restrict__ Wr_,
                                                    const float* __restrict__ brv,
                                                    float* __restrict__ xl,
                                                    float* __restrict__ xr,
                                                    int N, int ntiles) {
    int t = threadIdx.x;
    int w = t >> 6, lane = t & 63, q = lane >> 4, cl = lane & 15;

    // ---- B fragments: gathered from global once, resident in VGPRs ----
    bf16x8 Bh[2][4], Bl[2][4];
    float biasv[2];
    float* outp[2];
    int colc[2];
#pragma unroll
    for (int nt = 0; nt < 2; nt++) {
        int col = w * 32 + nt * 16 + cl;
        const float* Wsrc;
        int cw;
        if (col < 128) { Wsrc = Wl_; cw = col; biasv[nt] = blv[col]; outp[nt] = xl; colc[nt] = col; }
        else           { Wsrc = Wr_; cw = col - 128; biasv[nt] = brv[cw]; outp[nt] = xr; colc[nt] = cw; }
#pragma unroll
        for (int kt = 0; kt < 4; kt++) {
            int kb = kt * 32 + q * 8;
            float4 f0, f1;
            float ftmp[8];
#pragma unroll
            for (int j = 0; j < 8; j++) ftmp[j] = Wsrc[(size_t)(kb + j) * 128 + cw];
            f0 = make_float4(ftmp[0], ftmp[1], ftmp[2], ftmp[3]);
            f1 = make_float4(ftmp[4], ftmp[5], ftmp[6], ftmp[7]);
            cvt8(f0, f1, Bh[nt][kt], Bl[nt][kt]);
        }
    }

    int rt = blockIdx.x;
    if (rt >= ntiles) return;
    float4 cur[8], nxt[8];
    {
        int row = rt * 16 + cl;
        if (row >= N) row = N - 1;
        const float* ap = x + (size_t)row * 128 + q * 8;
#pragma unroll
        for (int kt = 0; kt < 4; kt++) {
            cur[2 * kt]     = *(const float4*)(ap + kt * 32);
            cur[2 * kt + 1] = *(const float4*)(ap + kt * 32 + 4);
        }
    }

    for (; rt < ntiles; rt += gridDim.x) {
        int rn = rt + gridDim.x;
        if (rn < ntiles) {
            int row = rn * 16 + cl;
            if (row >= N) row = N - 1;
            const float* ap = x + (size_t)row * 128 + q * 8;
#pragma unroll
            for (int kt = 0; kt < 4; kt++) {
                nxt[2 * kt]     = *(const float4*)(ap + kt * 32);
                nxt[2 * kt + 1] = *(const float4*)(ap + kt * 32 + 4);
            }
        }

        bf16x8 Ah[4], Al[4];
#pragma unroll
        for (int kt = 0; kt < 4; kt++) cvt8(cur[2 * kt], cur[2 * kt + 1], Ah[kt], Al[kt]);

        f32x4 acc0 = {0.f, 0.f, 0.f, 0.f}, acc1 = {0.f, 0.f, 0.f, 0.f};
#pragma unroll
        for (int kt = 0; kt < 4; kt++) {
            acc0 = __builtin_amdgcn_mfma_f32_16x16x32_bf16(Ah[kt], Bh[0][kt], acc0, 0, 0, 0);
            acc1 = __builtin_amdgcn_mfma_f32_16x16x32_bf16(Ah[kt], Bh[1][kt], acc1, 0, 0, 0);
            acc0 = __builtin_amdgcn_mfma_f32_16x16x32_bf16(Al[kt], Bh[0][kt], acc0, 0, 0, 0);
            acc1 = __builtin_amdgcn_mfma_f32_16x16x32_bf16(Al[kt], Bh[1][kt], acc1, 0, 0, 0);
            acc0 = __builtin_amdgcn_mfma_f32_16x16x32_bf16(Ah[kt], Bl[0][kt], acc0, 0, 0, 0);
            acc1 = __builtin_amdgcn_mfma_f32_16x16x32_bf16(Ah[kt], Bl[1][kt], acc1, 0, 0, 0);
        }

        // C/D layout: col = lane&15, row = quad*4 + reg  [m89-verified]
#pragma unroll
        for (int nt = 0; nt < 2; nt++) {
            f32x4 a = nt ? acc1 : acc0;
#pragma unroll
            for (int r = 0; r < 4; r++) {
                int row = rt * 16 + q * 4 + r;
                if (row < N) outp[nt][(size_t)row * 128 + colc[nt]] = a[r] + biasv[nt];
            }
        }
#pragma unroll
        for (int j = 0; j < 8; j++) cur[j] = nxt[j];
    }
}

// ---------------- GATv2 aggregation: 4 edges per wave-iteration ----------------
// Wave = 1 node. sub = lane>>4 picks edge 4g+sub; cl = lane&15 holds dims 8cl..8cl+7.
// Head h = cl>>1 (2 lanes/head): head-sum = 1 shfl_xor. Softmax without running max
// (logits clamped to +-80). Final cross-sub combine with shfl_xor 16/32.

__global__ __launch_bounds__(256) void gat_agg(const float4* __restrict__ xl4,
                                               const float4* __restrict__ xr4,
                                               const int* __restrict__ off,
                                               const int* __restrict__ esrc,
                                               const float4* __restrict__ att4,
                                               const float4* __restrict__ bias4,
                                               float4* __restrict__ out4, int N) {
    int lane = threadIdx.x & 63;
    int sub = lane >> 4;
    int cl = lane & 15;
    int i = blockIdx.x * 4 + (threadIdx.x >> 6);
    if (i >= N) return;

    float4 xrA = xr4[(size_t)i * 32 + 2 * cl];
    float4 xrB = xr4[(size_t)i * 32 + 2 * cl + 1];
    float4 atA = att4[2 * cl];
    float4 atB = att4[2 * cl + 1];
    int start = off[i];
    int total = off[i + 1] - start + 1;   // + self-loop (slot 0)
    int groups = (total + 3) >> 2;

    float s = 0.f;
    float4 aA = make_float4(0.f, 0.f, 0.f, 0.f);
    float4 aB = make_float4(0.f, 0.f, 0.f, 0.f);

    int k = sub;
    int src = (k < total) ? ((k == 0) ? i : esrc[start + k - 1]) : i;
    float4 vA = xl4[(size_t)src * 32 + 2 * cl];
    float4 vB = xl4[(size_t)src * 32 + 2 * cl + 1];
    int valid = (k < total);

    for (int g = 0; g < groups; g++) {
        int kn = 4 * (g + 1) + sub;
        int srcn = (kn < total) ? esrc[start + kn - 1] : i;
        float4 wA = xl4[(size_t)srcn * 32 + 2 * cl];
        float4 wB = xl4[(size_t)srcn * 32 + 2 * cl + 1];

        float z0 = vA.x + xrA.x, z1 = vA.y + xrA.y, z2 = vA.z + xrA.z, z3 = vA.w + xrA.w;
        float z4 = vB.x + xrB.x, z5 = vB.y + xrB.y, z6 = vB.z + xrB.z, z7 = vB.w + xrB.w;
        z0 = (z0 > 0.f) ? z0 : 0.2f * z0;
        z1 = (z1 > 0.f) ? z1 : 0.2f * z1;
        z2 = (z2 > 0.f) ? z2 : 0.2f * z2;
        z3 = (z3 > 0.f) ? z3 : 0.2f * z3;
        z4 = (z4 > 0.f) ? z4 : 0.2f * z4;
        z5 = (z5 > 0.f) ? z5 : 0.2f * z5;
        z6 = (z6 > 0.f) ? z6 : 0.2f * z6;
        z7 = (z7 > 0.f) ? z7 : 0.2f * z7;
        float p = z0 * atA.x + z1 * atA.y + z2 * atA.z + z3 * atA.w
                + z4 * atB.x + z5 * atB.y + z6 * atB.z + z7 * atB.w;
        p += __shfl_xor(p, 1, 64);            // head = 16 dims = 2 lanes
        p = fminf(fmaxf(p, -80.f), 80.f);
        float wgt = valid ? __expf(p) : 0.f;
        s += wgt;
        aA.x += wgt * vA.x; aA.y += wgt * vA.y; aA.z += wgt * vA.z; aA.w += wgt * vA.w;
        aB.x += wgt * vB.x; aB.y += wgt * vB.y; aB.z += wgt * vB.z; aB.w += wgt * vB.w;

        vA = wA; vB = wB;
        valid = (kn < total);
    }

#pragma unroll
    for (int o = 16; o <= 32; o <<= 1) {
        s += __shfl_xor(s, o, 64);
        aA.x += __shfl_xor(aA.x, o, 64); aA.y += __shfl_xor(aA.y, o, 64);
        aA.z += __shfl_xor(aA.z, o, 64); aA.w += __shfl_xor(aA.w, o, 64);
        aB.x += __shfl_xor(aB.x, o, 64); aB.y += __shfl_xor(aB.y, o, 64);
        aB.z += __shfl_xor(aB.z, o, 64); aB.w += __shfl_xor(aB.w, o, 64);
    }

    if (sub == 0) {
        float inv = 1.f / (s + 1e-16f);
        float4 bA = bias4[2 * cl], bB = bias4[2 * cl + 1];
        float4 oA, oB;
        oA.x = aA.x * inv + bA.x; oA.y = aA.y * inv + bA.y;
        oA.z = aA.z * inv + bA.z; oA.w = aA.w * inv + bA.w;
        oB.x = aB.x * inv + bB.x; oB.y = aB.y * inv + bB.y;
        oB.z = aB.z * inv + bB.z; oB.w = aB.w * inv + bB.w;
        out4[(size_t)i * 32 + 2 * cl] = oA;
        out4[(size_t)i * 32 + 2 * cl + 1] = oB;
    }
}

// ---------------- head ----------------

__global__ __launch_bounds__(128) void head_kernel(const float* __restrict__ x,
                                                   const float* __restrict__ w,
                                                   const float* __restrict__ bh,
                                                   const int* __restrict__ nch,
                                                   float* __restrict__ out) {
    __shared__ float r[2];
    int b = blockIdx.x, t = threadIdx.x;
    int chunk = 2 + nch[0];
    int row = (b >> 1) * chunk + (b & 1);
    float p = x[(size_t)row * 128 + t] * w[t];
#pragma unroll
    for (int o = 32; o >= 1; o >>= 1) p += __shfl_xor(p, o, 64);
    if ((t & 63) == 0) r[t >> 6] = p;
    __syncthreads();
    if (t == 0) out[b] = r[0] + r[1] + bh[0];
}

// ---------------- launch ----------------

extern "C" void kernel_launch(void* const* d_in, const int* in_sizes, int n_in,
                              void* d_out, int out_size, void* d_ws, size_t ws_size,
                              hipStream_t stream) {
    const float* x0 = (const float*)d_in[0];
    const int* ei = (const int*)d_in[1];
    const int* nchunks = (const int*)d_in[2];
    const float* Wl = (const float*)d_in[3];
    const float* bl = (const float*)d_in[4];
    const float* Wr = (const float*)d_in[5];
    const float* br = (const float*)d_in[6];
    const float* att = (const float*)d_in[7];
    const float* bias = (const float*)d_in[8];
    const float* wh = (const float*)d_in[9];
    const float* bh = (const float*)d_in[10];

    const int D = 128;
    int N = in_sizes[0] / D;   // 10000
    int E = in_sizes[1] / 2;   // 160000
    int ntiles = (N + 15) / 16;

    size_t fN = (size_t)N * D;
    float* xl = (float*)d_ws;
    float* xr = xl + fN;
    float* xA = xr + fN;
    int* deg = (int*)(xA + fN);
    int* off = deg + N;
    int* cur = off + N + 1;
    int* esrc = cur + N;

    hipMemsetAsync(deg, 0, (size_t)N * sizeof(int), stream);
    count_kernel<<<(E + NT - 1) / NT, NT, 0, stream>>>(ei, E, N, deg);
    scan_kernel<<<1, 256, 0, stream>>>(deg, off, cur, N);
    fill_kernel<<<(E + NT - 1) / NT, NT, 0, stream>>>(ei, E, N, cur, esrc);

    int aggblocks = (N + 3) / 4;
    const float* xc = x0;
    for (int l = 0; l < 7; l++) {
        gemm_xlxr<<<256, 512, 0, stream>>>(xc, Wl + (size_t)l * D * D, bl + (size_t)l * D,
                                           Wr + (size_t)l * D * D, br + (size_t)l * D,
                                           xl, xr, N, ntiles);
        gat_agg<<<aggblocks, 256, 0, stream>>>((const float4*)xl, (const float4*)xr, off, esrc,
                                               (const float4*)(att + (size_t)l * D),
                                               (const float4*)(bias + (size_t)l * D),
                                               (float4*)xA, N);
        xc = xA;
    }

    head_kernel<<<out_size, 128, 0, stream>>>(xc, wh, bh, nchunks, (float*)d_out);
}

// Round 5
// 331.129 us; speedup vs baseline: 1.6366x; 1.0006x over previous
//
#include <hip/hip_runtime.h>
#include <math.h>

#define NT 256

typedef __attribute__((ext_vector_type(8))) short bf16x8;
typedef __attribute__((ext_vector_type(4))) float f32x4;

// ---------------- CSR build ----------------

__device__ inline int detect_is64(const int* __restrict__ ei) {
    // int64 little-endian => odd int32 words (high words) are all 0 for values < 2^31
    int is64 = 1;
#pragma unroll
    for (int k = 1; k < 16; k += 2) is64 &= (ei[k] == 0);
    return is64;
}

__global__ void count_kernel(const int* __restrict__ ei, int E, int N,
                             int* __restrict__ deg) {
    int e = blockIdx.x * blockDim.x + threadIdx.x;
    if (e >= E) return;
    int is64 = detect_is64(ei);
    long long pos = (long long)E + e;
    int d = ei[is64 ? 2 * pos : pos];
    if ((unsigned)d < (unsigned)N) atomicAdd(&deg[d], 1);
}

__global__ __launch_bounds__(256) void scan_kernel(const int* __restrict__ deg,
                                                   int* __restrict__ off,
                                                   int* __restrict__ cur, int N) {
    __shared__ int wsum[4];
    int t = threadIdx.x;
    int per = (N + 255) >> 8;
    int b0 = t * per;
    int s = 0;
    for (int k = 0; k < per; k++) {
        int idx = b0 + k;
        if (idx < N) s += deg[idx];
    }
    int lane = t & 63, w = t >> 6;
    int v = s;
#pragma unroll
    for (int o = 1; o < 64; o <<= 1) {
        int u = __shfl_up(v, o, 64);
        if (lane >= o) v += u;
    }
    if (lane == 63) wsum[w] = v;
    __syncthreads();
    if (t == 0) {
        int r = 0;
#pragma unroll
        for (int j = 0; j < 4; j++) { int xx = wsum[j]; wsum[j] = r; r += xx; }
        off[N] = r;
    }
    __syncthreads();
    int run = v - s + wsum[w];   // exclusive prefix for this thread
    for (int k = 0; k < per; k++) {
        int idx = b0 + k;
        if (idx < N) {
            off[idx] = run;
            cur[idx] = run;
            run += deg[idx];
        }
    }
}

__global__ void fill_kernel(const int* __restrict__ ei, int E, int N,
                            int* __restrict__ cur, int* __restrict__ esrc) {
    int e = blockIdx.x * blockDim.x + threadIdx.x;
    if (e >= E) return;
    int is64 = detect_is64(ei);
    long long spos = e;
    long long dpos = (long long)E + e;
    int s = ei[is64 ? 2 * spos : spos];
    int d = ei[is64 ? 2 * dpos : dpos];
    if ((unsigned)d >= (unsigned)N || (unsigned)s >= (unsigned)N) return;
    int p = atomicAdd(&cur[d], 1);
    esrc[p] = s;
}

// ---------------- GEMM via bf16x3 MFMA (no LDS, no barriers) ----------------
// D = x @ [Wl | Wr] (K=128, 256 cols) with fp32 emulated as A_hi*B_hi + A_lo*B_hi + A_hi*B_lo.
// Grid 256 x 512 threads; wave w owns cols [32w,32w+32) as two 16x16 MFMA col-tiles.
// B fragments (hi+lo, full K) live in VGPRs for the whole kernel. A loads stream
// from global (16B/lane) with 1-deep row-tile pipeline. Stores direct to xl/xr.
// NOTE __launch_bounds__(512,1): reg demand ~190 VGPR; (512,2) would cap at 128
// and spill the A pipeline to scratch inside the loop.

__device__ inline void cvt8(const float4& a, const float4& b, bf16x8& hi, bf16x8& lo) {
    float f[8] = {a.x, a.y, a.z, a.w, b.x, b.y, b.z, b.w};
#pragma unroll
    for (int j = 0; j < 8; j++) {
        unsigned u = __float_as_uint(f[j]);
        hi[j] = (short)(u >> 16);                         // truncate to bf16
        float fl = f[j] - __uint_as_float(u & 0xffff0000u);
        lo[j] = (short)(__float_as_uint(fl) >> 16);       // residual, truncated
    }
}

__global__ __launch_bounds__(512, 1) void gemm_xlxr(const float* __restrict__ x,
                                                    const float* __restrict__ Wl_,
                                                    const float* __restrict__ blv,
                                                    const float* __restrict__ Wr_,
                                                    const float* __restrict__ brv,
                                                    float* __restrict__ xl,
                                                    float* __restrict__ xr,
                                                    int N, int ntiles) {
    int t = threadIdx.x;
    int w = t >> 6, lane = t & 63, q = lane >> 4, cl = lane & 15;

    // ---- B fragments: gathered from global once, resident in VGPRs ----
    bf16x8 Bh[2][4], Bl[2][4];
    float biasv[2];
    float* outp[2];
    int colc[2];
#pragma unroll
    for (int nt = 0; nt < 2; nt++) {
        int col = w * 32 + nt * 16 + cl;
        const float* Wsrc;
        int cw;
        if (col < 128) { Wsrc = Wl_; cw = col; biasv[nt] = blv[col]; outp[nt] = xl; colc[nt] = col; }
        else           { Wsrc = Wr_; cw = col - 128; biasv[nt] = brv[cw]; outp[nt] = xr; colc[nt] = cw; }
#pragma unroll
        for (int kt = 0; kt < 4; kt++) {
            int kb = kt * 32 + q * 8;
            float4 f0, f1;
            float ftmp[8];
#pragma unroll
            for (int j = 0; j < 8; j++) ftmp[j] = Wsrc[(size_t)(kb + j) * 128 + cw];
            f0 = make_float4(ftmp[0], ftmp[1], ftmp[2], ftmp[3]);
            f1 = make_float4(ftmp[4], ftmp[5], ftmp[6], ftmp[7]);
            cvt8(f0, f1, Bh[nt][kt], Bl[nt][kt]);
        }
    }

    int rt = blockIdx.x;
    if (rt >= ntiles) return;
    float4 cur[8], nxt[8];
    {
        int row = rt * 16 + cl;
        if (row >= N) row = N - 1;
        const float* ap = x + (size_t)row * 128 + q * 8;
#pragma unroll
        for (int kt = 0; kt < 4; kt++) {
            cur[2 * kt]     = *(const float4*)(ap + kt * 32);
            cur[2 * kt + 1] = *(const float4*)(ap + kt * 32 + 4);
        }
    }

    for (; rt < ntiles; rt += gridDim.x) {
        int rn = rt + gridDim.x;
        if (rn < ntiles) {
            int row = rn * 16 + cl;
            if (row >= N) row = N - 1;
            const float* ap = x + (size_t)row * 128 + q * 8;
#pragma unroll
            for (int kt = 0; kt < 4; kt++) {
                nxt[2 * kt]     = *(const float4*)(ap + kt * 32);
                nxt[2 * kt + 1] = *(const float4*)(ap + kt * 32 + 4);
            }
        }

        bf16x8 Ah[4], Al[4];
#pragma unroll
        for (int kt = 0; kt < 4; kt++) cvt8(cur[2 * kt], cur[2 * kt + 1], Ah[kt], Al[kt]);

        f32x4 acc0 = {0.f, 0.f, 0.f, 0.f}, acc1 = {0.f, 0.f, 0.f, 0.f};
#pragma unroll
        for (int kt = 0; kt < 4; kt++) {
            acc0 = __builtin_amdgcn_mfma_f32_16x16x32_bf16(Ah[kt], Bh[0][kt], acc0, 0, 0, 0);
            acc1 = __builtin_amdgcn_mfma_f32_16x16x32_bf16(Ah[kt], Bh[1][kt], acc1, 0, 0, 0);
            acc0 = __builtin_amdgcn_mfma_f32_16x16x32_bf16(Al[kt], Bh[0][kt], acc0, 0, 0, 0);
            acc1 = __builtin_amdgcn_mfma_f32_16x16x32_bf16(Al[kt], Bh[1][kt], acc1, 0, 0, 0);
            acc0 = __builtin_amdgcn_mfma_f32_16x16x32_bf16(Ah[kt], Bl[0][kt], acc0, 0, 0, 0);
            acc1 = __builtin_amdgcn_mfma_f32_16x16x32_bf16(Ah[kt], Bl[1][kt], acc1, 0, 0, 0);
        }

        // C/D layout: col = lane&15, row = quad*4 + reg  [m89-verified]
#pragma unroll
        for (int nt = 0; nt < 2; nt++) {
            f32x4 a = nt ? acc1 : acc0;
#pragma unroll
            for (int r = 0; r < 4; r++) {
                int row = rt * 16 + q * 4 + r;
                if (row < N) outp[nt][(size_t)row * 128 + colc[nt]] = a[r] + biasv[nt];
            }
        }
#pragma unroll
        for (int j = 0; j < 8; j++) cur[j] = nxt[j];
    }
}

// ---------------- GATv2 aggregation: 4 edges per wave-iteration ----------------

__global__ __launch_bounds__(256) void gat_agg(const float4* __restrict__ xl4,
                                               const float4* __restrict__ xr4,
                                               const int* __restrict__ off,
                                               const int* __restrict__ esrc,
                                               const float4* __restrict__ att4,
                                               const float4* __restrict__ bias4,
                                               float4* __restrict__ out4, int N) {
    int lane = threadIdx.x & 63;
    int sub = lane >> 4;
    int cl = lane & 15;
    int i = blockIdx.x * 4 + (threadIdx.x >> 6);
    if (i >= N) return;

    float4 xrA = xr4[(size_t)i * 32 + 2 * cl];
    float4 xrB = xr4[(size_t)i * 32 + 2 * cl + 1];
    float4 atA = att4[2 * cl];
    float4 atB = att4[2 * cl + 1];
    int start = off[i];
    int total = off[i + 1] - start + 1;   // + self-loop (slot 0)
    int groups = (total + 3) >> 2;

    float s = 0.f;
    float4 aA = make_float4(0.f, 0.f, 0.f, 0.f);
    float4 aB = make_float4(0.f, 0.f, 0.f, 0.f);

    int k = sub;
    int src = (k < total) ? ((k == 0) ? i : esrc[start + k - 1]) : i;
    float4 vA = xl4[(size_t)src * 32 + 2 * cl];
    float4 vB = xl4[(size_t)src * 32 + 2 * cl + 1];
    int valid = (k < total);

    for (int g = 0; g < groups; g++) {
        int kn = 4 * (g + 1) + sub;
        int srcn = (kn < total) ? esrc[start + kn - 1] : i;
        float4 wA = xl4[(size_t)srcn * 32 + 2 * cl];
        float4 wB = xl4[(size_t)srcn * 32 + 2 * cl + 1];

        float z0 = vA.x + xrA.x, z1 = vA.y + xrA.y, z2 = vA.z + xrA.z, z3 = vA.w + xrA.w;
        float z4 = vB.x + xrB.x, z5 = vB.y + xrB.y, z6 = vB.z + xrB.z, z7 = vB.w + xrB.w;
        z0 = (z0 > 0.f) ? z0 : 0.2f * z0;
        z1 = (z1 > 0.f) ? z1 : 0.2f * z1;
        z2 = (z2 > 0.f) ? z2 : 0.2f * z2;
        z3 = (z3 > 0.f) ? z3 : 0.2f * z3;
        z4 = (z4 > 0.f) ? z4 : 0.2f * z4;
        z5 = (z5 > 0.f) ? z5 : 0.2f * z5;
        z6 = (z6 > 0.f) ? z6 : 0.2f * z6;
        z7 = (z7 > 0.f) ? z7 : 0.2f * z7;
        float p = z0 * atA.x + z1 * atA.y + z2 * atA.z + z3 * atA.w
                + z4 * atB.x + z5 * atB.y + z6 * atB.z + z7 * atB.w;
        p += __shfl_xor(p, 1, 64);            // head = 16 dims = 2 lanes
        p = fminf(fmaxf(p, -80.f), 80.f);
        float wgt = valid ? __expf(p) : 0.f;
        s += wgt;
        aA.x += wgt * vA.x; aA.y += wgt * vA.y; aA.z += wgt * vA.z; aA.w += wgt * vA.w;
        aB.x += wgt * vB.x; aB.y += wgt * vB.y; aB.z += wgt * vB.z; aB.w += wgt * vB.w;

        vA = wA; vB = wB;
        valid = (kn < total);
    }

#pragma unroll
    for (int o = 16; o <= 32; o <<= 1) {
        s += __shfl_xor(s, o, 64);
        aA.x += __shfl_xor(aA.x, o, 64); aA.y += __shfl_xor(aA.y, o, 64);
        aA.z += __shfl_xor(aA.z, o, 64); aA.w += __shfl_xor(aA.w, o, 64);
        aB.x += __shfl_xor(aB.x, o, 64); aB.y += __shfl_xor(aB.y, o, 64);
        aB.z += __shfl_xor(aB.z, o, 64); aB.w += __shfl_xor(aB.w, o, 64);
    }

    if (sub == 0) {
        float inv = 1.f / (s + 1e-16f);
        float4 bA = bias4[2 * cl], bB = bias4[2 * cl + 1];
        float4 oA, oB;
        oA.x = aA.x * inv + bA.x; oA.y = aA.y * inv + bA.y;
        oA.z = aA.z * inv + bA.z; oA.w = aA.w * inv + bA.w;
        oB.x = aB.x * inv + bB.x; oB.y = aB.y * inv + bB.y;
        oB.z = aB.z * inv + bB.z; oB.w = aB.w * inv + bB.w;
        out4[(size_t)i * 32 + 2 * cl] = oA;
        out4[(size_t)i * 32 + 2 * cl + 1] = oB;
    }
}

// ---------------- head ----------------

__global__ __launch_bounds__(128) void head_kernel(const float* __restrict__ x,
                                                   const float* __restrict__ w,
                                                   const float* __restrict__ bh,
                                                   const int* __restrict__ nch,
                                                   float* __restrict__ out) {
    __shared__ float r[2];
    int b = blockIdx.x, t = threadIdx.x;
    int chunk = 2 + nch[0];
    int row = (b >> 1) * chunk + (b & 1);
    float p = x[(size_t)row * 128 + t] * w[t];
#pragma unroll
    for (int o = 32; o >= 1; o >>= 1) p += __shfl_xor(p, o, 64);
    if ((t & 63) == 0) r[t >> 6] = p;
    __syncthreads();
    if (t == 0) out[b] = r[0] + r[1] + bh[0];
}

// ---------------- launch ----------------

extern "C" void kernel_launch(void* const* d_in, const int* in_sizes, int n_in,
                              void* d_out, int out_size, void* d_ws, size_t ws_size,
                              hipStream_t stream) {
    const float* x0 = (const float*)d_in[0];
    const int* ei = (const int*)d_in[1];
    const int* nchunks = (const int*)d_in[2];
    const float* Wl = (const float*)d_in[3];
    const float* bl = (const float*)d_in[4];
    const float* Wr = (const float*)d_in[5];
    const float* br = (const float*)d_in[6];
    const float* att = (const float*)d_in[7];
    const float* bias = (const float*)d_in[8];
    const float* wh = (const float*)d_in[9];
    const float* bh = (const float*)d_in[10];

    const int D = 128;
    int N = in_sizes[0] / D;   // 10000
    int E = in_sizes[1] / 2;   // 160000
    int ntiles = (N + 15) / 16;

    size_t fN = (size_t)N * D;
    float* xl = (float*)d_ws;
    float* xr = xl + fN;
    float* xA = xr + fN;
    int* deg = (int*)(xA + fN);
    int* off = deg + N;
    int* cur = off + N + 1;
    int* esrc = cur + N;

    hipMemsetAsync(deg, 0, (size_t)N * sizeof(int), stream);
    count_kernel<<<(E + NT - 1) / NT, NT, 0, stream>>>(ei, E, N, deg);
    scan_kernel<<<1, 256, 0, stream>>>(deg, off, cur, N);
    fill_kernel<<<(E + NT - 1) / NT, NT, 0, stream>>>(ei, E, N, cur, esrc);

    int aggblocks = (N + 3) / 4;
    const float* xc = x0;
    for (int l = 0; l < 7; l++) {
        gemm_xlxr<<<256, 512, 0, stream>>>(xc, Wl + (size_t)l * D * D, bl + (size_t)l * D,
                                           Wr + (size_t)l * D * D, br + (size_t)l * D,
                                           xl, xr, N, ntiles);
        gat_agg<<<aggblocks, 256, 0, stream>>>((const float4*)xl, (const float4*)xr, off, esrc,
                                               (const float4*)(att + (size_t)l * D),
                                               (const float4*)(bias + (size_t)l * D),
                                               (float4*)xA, N);
        xc = xA;
    }

    head_kernel<<<out_size, 128, 0, stream>>>(xc, wh, bh, nchunks, (float*)d_out);
}